// Round 1
// baseline (687.156 us; speedup 1.0000x reference)
//
#include <hip/hip_runtime.h>
#include <math.h>

#define B_ 4
#define N_ 4096
#define K_ 16

// One wave (64 lanes) per query point. Lanes 0..15 hold the running top-16
// nearest (sorted ascending, lane 15 = worst = tau). Inserts are done with
// ballot + shfl_up shifts so the cost is ~15 instructions per insert and the
// scan loop itself is branch-light.
__global__ __launch_bounds__(256) void curv_kappa_kernel(
    const float* __restrict__ ori,
    const float* __restrict__ adv,
    const float* __restrict__ nrm,
    double* __restrict__ acc)   // acc[row*2 + {0,1}] = sum, sumsq ; row = job*4+b
{
    const int lane = threadIdx.x & 63;
    const int wid  = blockIdx.x * 4 + (threadIdx.x >> 6);
    const int job  = wid >> 14;          // 0 = ori set, 1 = adv set
    const int q    = wid & 16383;
    const int b    = q >> 12;
    const int n    = q & 4095;

    const float* pts  = (job ? adv : ori) + (size_t)b * (N_ * 3);
    const float* nrmb = nrm + (size_t)b * (N_ * 3);

    const float qx = pts[3*n+0];
    const float qy = pts[3*n+1];
    const float qz = pts[3*n+2];

    // ---- normal for this query ----
    float nrx, nry, nrz;
    if (job == 0) {
        nrx = nrmb[3*n+0]; nry = nrmb[3*n+1]; nrz = nrmb[3*n+2];
    } else {
        // argmin over ori points (sqdist(adv, ori)), tie -> lowest index
        const float* op = ori + (size_t)b * (N_ * 3);
        float dm = __builtin_huge_valf();
        int   jm = 0;
        #pragma unroll 4
        for (int t = 0; t < N_/64; ++t) {
            int j = t*64 + lane;
            float dx = qx - op[3*j+0];
            float dy = qy - op[3*j+1];
            float dz = qz - op[3*j+2];
            float d  = dx*dx + dy*dy + dz*dz;
            bool better = d < dm;       // strict: keeps earliest j in lane's stream
            dm = better ? d : dm;
            jm = better ? j : jm;
        }
        // cross-lane lexicographic (d, idx) min
        for (int s = 1; s < 64; s <<= 1) {
            float od = __shfl_xor(dm, s);
            int   oj = __shfl_xor(jm, s);
            if (od < dm || (od == dm && oj < jm)) { dm = od; jm = oj; }
        }
        nrx = nrmb[3*jm+0]; nry = nrmb[3*jm+1]; nrz = nrmb[3*jm+2];
    }

    // ---- distributed top-16 self-kNN over pts ----
    float sd  = __builtin_huge_valf();   // lane l (<16): l-th smallest distance
    int   si  = 0x7fffffff;              // its candidate index
    float tau = __builtin_huge_valf();   // current 16th-smallest (lane 15)

    for (int t = 0; t < N_/64; ++t) {
        int j = t*64 + lane;
        float dx = qx - pts[3*j+0];
        float dy = qy - pts[3*j+1];
        float dz = qz - pts[3*j+2];
        float d  = dx*dx + dy*dy + dz*dz;
        if (j == n) d = __builtin_huge_valf();   // exclude self (ref drops nearest = self, d==0)

        unsigned long long mask = __ballot(d < tau);
        while (mask) {                   // wave-uniform loop
            int src = __builtin_ctzll(mask);
            mask &= mask - 1;
            float v = __shfl(d, src);    // uniform broadcast of the passing candidate
            if (v < tau) {               // re-check against updated tau
                int vi = t*64 + src;
                // insert (v, vi) into the distributed sorted list
                bool gt = (sd > v) || (sd == v && si > vi);   // index tie-break like top_k
                unsigned long long mg = __ballot(gt);
                float usd = __shfl_up(sd, 1);
                int   usi = __shfl_up(si, 1);
                bool  pg  = ((mg << 1) >> lane) & 1ull;       // did lane-1 also shift?
                sd = gt ? (pg ? usd : v)  : sd;
                si = gt ? (pg ? usi : vi) : si;
                tau = __shfl(sd, 15);
            }
        }
    }

    // ---- kappa = mean_k |dot(normalize(nn - q), normal)| ----
    float tl = 0.0f;
    if (lane < K_) {
        float vx = pts[3*si+0] - qx;
        float vy = pts[3*si+1] - qy;
        float vz = pts[3*si+2] - qz;
        float L  = sqrtf(vx*vx + vy*vy + vz*vz) + 1e-12f;
        tl = fabsf(vx*nrx + vy*nry + vz*nrz) / L;
    }
    tl += __shfl_xor(tl, 1);
    tl += __shfl_xor(tl, 2);
    tl += __shfl_xor(tl, 4);
    tl += __shfl_xor(tl, 8);   // lanes 16..63 contribute 0 within their 16-groups

    if (lane == 0) {
        double kap = (double)(tl * (1.0f / 16.0f));
        int row = job * 4 + b;
        atomicAdd(&acc[row*2+0], kap);
        atomicAdd(&acc[row*2+1], kap * kap);
    }
}

__global__ void curv_finalize_kernel(const double* __restrict__ acc,
                                     float* __restrict__ out)
{
    if (threadIdx.x == 0 && blockIdx.x == 0) {
        double st[8];
        #pragma unroll
        for (int r = 0; r < 8; ++r) {
            double s   = acc[2*r+0];
            double ss  = acc[2*r+1];
            double var = (ss - s*s / (double)N_) / (double)(N_ - 1);
            st[r] = var > 0.0 ? sqrt(var) : 0.0;
        }
        double o = 0.0;
        #pragma unroll
        for (int bb = 0; bb < 4; ++bb) o += fabs(st[4+bb] - st[bb]);
        out[0] = (float)(o * 0.25);
    }
}

extern "C" void kernel_launch(void* const* d_in, const int* in_sizes, int n_in,
                              void* d_out, int out_size, void* d_ws, size_t ws_size,
                              hipStream_t stream)
{
    const float* ori = (const float*)d_in[0];
    const float* adv = (const float*)d_in[1];
    const float* nrm = (const float*)d_in[2];
    double* acc = (double*)d_ws;
    float*  out = (float*)d_out;

    hipMemsetAsync(acc, 0, 16 * sizeof(double), stream);

    // 2 jobs * B * N query-waves, 4 waves per 256-thread block
    dim3 grid(2 * B_ * N_ / 4);
    curv_kappa_kernel<<<grid, 256, 0, stream>>>(ori, adv, nrm, acc);
    curv_finalize_kernel<<<1, 64, 0, stream>>>(acc, out);
}

// Round 2
// 271.275 us; speedup vs baseline: 2.5331x; 2.5331x over previous
//
#include <hip/hip_runtime.h>
#include <math.h>

#define B_ 4
#define N_ 4096
#define K_ 16
#define WAVES 4
#define QPW 2                    // queries per wave
#define QPB (WAVES*QPW)          // 8 queries per block
#define BPB (N_/QPB)             // 512 blocks per (job,b)
#define INF __builtin_huge_valf()

// shift value from lane-1 within each 16-lane row (lane%16==0 keeps own).
// Only lanes 0..15 of the distributed top-16 list need a true shift, so
// row_shr:1 (universally supported DPP) is sufficient — no ds_bpermute.
__device__ __forceinline__ float dpp_shr1_f(float x) {
    return __int_as_float(__builtin_amdgcn_update_dpp(
        __float_as_int(x), __float_as_int(x), 0x111, 0xF, 0xF, false));
}
__device__ __forceinline__ int dpp_shr1_i(int x) {
    return __builtin_amdgcn_update_dpp(x, x, 0x111, 0xF, 0xF, false);
}
__device__ __forceinline__ float readlane_f(float x, int l) {
    return __int_as_float(__builtin_amdgcn_readlane(__float_as_int(x), l));
}

// ---------------- argmin(adv -> ori) : nn index per adv point ----------------
__global__ __launch_bounds__(256, 3) void curv_argmin_kernel(
    const float* __restrict__ ori, const float* __restrict__ adv,
    int* __restrict__ nnidx)
{
    __shared__ float2 sxy[N_];
    __shared__ float  sz[N_];
    const int tid  = threadIdx.x;
    const int lane = tid & 63;
    const int w    = tid >> 6;
    const int b    = blockIdx.x >> 9;           // 512 blocks per batch
    const int qb   = (blockIdx.x & 511) * QPB;

    const float* ob = ori + (size_t)b * (N_*3);
    const float* ab = adv + (size_t)b * (N_*3);
    for (int k = 0; k < N_/256; ++k) {          // stage ori[b] -> LDS
        int j = k*256 + tid;
        sxy[j] = make_float2(ob[3*j+0], ob[3*j+1]);
        sz[j]  = ob[3*j+2];
    }
    __syncthreads();

    for (int qi = 0; qi < QPW; ++qi) {
        const int n  = qb + w*QPW + qi;
        const float qx = ab[3*n+0], qy = ab[3*n+1], qz = ab[3*n+2];
        float dm = INF; int jm = 0;
        for (int t = 0; t < N_/64; ++t) {
            int j = t*64 + lane;
            float2 p = sxy[j]; float pz = sz[j];
            float dx = qx - p.x, dy = qy - p.y, dz = qz - pz;
            float d  = dx*dx + dy*dy + dz*dz;
            bool better = d < dm;               // keeps lowest index in-lane
            dm = better ? d : dm;
            jm = better ? j : jm;
        }
        for (int s = 1; s < 64; s <<= 1) {      // lexicographic (d, idx) min
            float od = __shfl_xor(dm, s);
            int   oj = __shfl_xor(jm, s);
            if (od < dm || (od == dm && oj < jm)) { dm = od; jm = oj; }
        }
        if (lane == 0) nnidx[b*N_ + n] = jm;
    }
}

// ---------------- kappa for both sets, accumulate (sum, sumsq) ---------------
__global__ __launch_bounds__(256, 3) void curv_kappa_kernel(
    const float* __restrict__ ori, const float* __restrict__ adv,
    const float* __restrict__ nrm, const int* __restrict__ nnidx,
    double* __restrict__ acc)
{
    __shared__ float2 sxy[N_];
    __shared__ float  sz[N_];
    __shared__ double rs[WAVES], rss[WAVES];
    const int tid  = threadIdx.x;
    const int lane = tid & 63;
    const int w    = tid >> 6;
    const int blk  = blockIdx.x;
    const int job  = blk >> 11;                 // 2048 blocks per job
    const int b    = (blk >> 9) & 3;
    const int qb   = (blk & 511) * QPB;

    const float* pb = (job ? adv : ori) + (size_t)b * (N_*3);
    const float* nb = nrm + (size_t)b * (N_*3);
    for (int k = 0; k < N_/256; ++k) {          // stage pts -> LDS
        int j = k*256 + tid;
        sxy[j] = make_float2(pb[3*j+0], pb[3*j+1]);
        sz[j]  = pb[3*j+2];
    }
    __syncthreads();

    double ws_s = 0.0, ws_ss = 0.0;
    for (int qi = 0; qi < QPW; ++qi) {
        const int n = qb + w*QPW + qi;
        const float2 qxy = sxy[n];
        const float  qz  = sz[n];
        int nn = n;
        if (job) nn = nnidx[b*N_ + n];
        const float nrx = nb[3*nn+0], nry = nb[3*nn+1], nrz = nb[3*nn+2];

        // ---- tile 0: bitonic sort 64 (d, idx) ascending ----
        float d; int idx = lane;
        {
            float2 p = sxy[lane]; float pz = sz[lane];
            float dx = qxy.x - p.x, dy = qxy.y - p.y, dz = qz - pz;
            d = dx*dx + dy*dy + dz*dz;
            if (lane == n) d = INF;             // exclude self
        }
        #pragma unroll
        for (int k = 2; k <= 64; k <<= 1) {
            #pragma unroll
            for (int j = k >> 1; j > 0; j >>= 1) {
                float od = __shfl_xor(d, j);
                int   oi = __shfl_xor(idx, j);
                bool dirUp = ((lane & k) == 0);
                bool lower = ((lane & j) == 0);
                bool oless = (od < d) || (od == d && oi < idx);
                bool take  = (dirUp == lower) ? oless : !oless;
                if (take) { d = od; idx = oi; }
            }
        }
        float sd = d; int si = idx;             // lanes 0..15: sorted top-16
        float tau = readlane_f(sd, 15);
        const int selfT = n >> 6, selfL = n & 63;

        // ---- tiles 1..63: ballot + distributed insert (tau deferred) ----
        for (int t = 1; t < N_/64; ++t) {
            int j = t*64 + lane;
            float2 p = sxy[j]; float pz = sz[j];
            float dx = qxy.x - p.x, dy = qxy.y - p.y, dz = qz - pz;
            float dd = dx*dx + dy*dy + dz*dz;
            if (t == selfT && lane == selfL) dd = INF;
            unsigned long long mask = __ballot(dd < tau);
            if (mask) {
                do {
                    int src = __builtin_ctzll(mask);
                    mask &= mask - 1;
                    float v = readlane_f(dd, src);       // SGPR broadcast
                    int  vi = t*64 + src;
                    bool gt = (sd > v) || (sd == v && si > vi);
                    unsigned long long mg = __ballot(gt);
                    float usd = dpp_shr1_f(sd);
                    int   usi = dpp_shr1_i(si);
                    bool  pg  = ((mg << 1) >> lane) & 1ull;
                    sd = gt ? (pg ? usd : v ) : sd;      // insert is a no-op
                    si = gt ? (pg ? usi : vi) : si;      // if v >= sd[15]
                } while (mask);
                tau = readlane_f(sd, 15);
            }
        }

        // ---- kappa = mean_k |dot(normalize(nn - q), normal)| ----
        float tl = 0.0f;
        if (lane < K_) {
            float2 p = sxy[si]; float pz = sz[si];
            float vx = p.x - qxy.x, vy = p.y - qxy.y, vz = pz - qz;
            float L  = sqrtf(vx*vx + vy*vy + vz*vz) + 1e-12f;
            tl = fabsf(vx*nrx + vy*nry + vz*nrz) / L;
        }
        tl += __shfl_xor(tl, 1);
        tl += __shfl_xor(tl, 2);
        tl += __shfl_xor(tl, 4);
        tl += __shfl_xor(tl, 8);
        if (lane == 0) {
            double kap = (double)tl * (1.0/16.0);
            ws_s  += kap;
            ws_ss += kap * kap;
        }
    }

    if (lane == 0) { rs[w] = ws_s; rss[w] = ws_ss; }
    __syncthreads();
    if (tid == 0) {
        double s  = rs[0] + rs[1] + rs[2] + rs[3];
        double ss = rss[0] + rss[1] + rss[2] + rss[3];
        int row = job*4 + b;
        atomicAdd(&acc[row*2+0], s);
        atomicAdd(&acc[row*2+1], ss);
    }
}

__global__ void curv_finalize_kernel(const double* __restrict__ acc,
                                     float* __restrict__ out)
{
    if (threadIdx.x == 0 && blockIdx.x == 0) {
        double st[8];
        #pragma unroll
        for (int r = 0; r < 8; ++r) {
            double s   = acc[2*r+0];
            double ss  = acc[2*r+1];
            double var = (ss - s*s / (double)N_) / (double)(N_ - 1);
            st[r] = var > 0.0 ? sqrt(var) : 0.0;
        }
        double o = 0.0;
        #pragma unroll
        for (int bb = 0; bb < 4; ++bb) o += fabs(st[4+bb] - st[bb]);
        out[0] = (float)(o * 0.25);
    }
}

extern "C" void kernel_launch(void* const* d_in, const int* in_sizes, int n_in,
                              void* d_out, int out_size, void* d_ws, size_t ws_size,
                              hipStream_t stream)
{
    const float* ori = (const float*)d_in[0];
    const float* adv = (const float*)d_in[1];
    const float* nrm = (const float*)d_in[2];
    double* acc   = (double*)d_ws;
    int*    nnidx = (int*)((char*)d_ws + 128);
    float*  out   = (float*)d_out;

    hipMemsetAsync(acc, 0, 16 * sizeof(double), stream);
    curv_argmin_kernel<<<dim3(B_ * BPB), 256, 0, stream>>>(ori, adv, nnidx);
    curv_kappa_kernel<<<dim3(2 * B_ * BPB), 256, 0, stream>>>(ori, adv, nrm, nnidx, acc);
    curv_finalize_kernel<<<1, 64, 0, stream>>>(acc, out);
}

// Round 3
// 146.395 us; speedup vs baseline: 4.6938x; 1.8530x over previous
//
#include <hip/hip_runtime.h>
#include <math.h>

#define B_ 4
#define N_ 4096
#define K_ 16
#define WAVES 8
#define QPW 2                    // queries per wave
#define QPB (WAVES*QPW)          // 16 queries per block
#define BPB (N_/QPB)             // 256 blocks per (job,b)
#define INF __builtin_huge_valf()

// shift value from lane-1 within each 16-lane row (lane%16==0 keeps own).
// Only lanes 0..15 of the distributed top-16 list need a true shift, so
// row_shr:1 DPP is sufficient — no ds_bpermute on the pop critical path.
__device__ __forceinline__ float dpp_shr1_f(float x) {
    return __int_as_float(__builtin_amdgcn_update_dpp(
        __float_as_int(x), __float_as_int(x), 0x111, 0xF, 0xF, false));
}
__device__ __forceinline__ int dpp_shr1_i(int x) {
    return __builtin_amdgcn_update_dpp(x, x, 0x111, 0xF, 0xF, false);
}
__device__ __forceinline__ float readlane_f(float x, int l) {
    return __int_as_float(__builtin_amdgcn_readlane(__float_as_int(x), l));
}

// ---------------- argmin(adv -> ori) : nn index per adv point ----------------
__global__ __launch_bounds__(512, 6) void curv_argmin_kernel(
    const float* __restrict__ ori, const float* __restrict__ adv,
    int* __restrict__ nnidx)
{
    __shared__ float2 sxy[N_];
    __shared__ float  sz[N_];
    const int tid  = threadIdx.x;
    const int lane = tid & 63;
    const int w    = tid >> 6;
    const int b    = blockIdx.x >> 8;           // 256 blocks per batch
    const int qb   = (blockIdx.x & 255) * QPB;

    const float* ob = ori + (size_t)b * (N_*3);
    const float* ab = adv + (size_t)b * (N_*3);
    for (int k = 0; k < N_/512; ++k) {          // stage ori[b] -> LDS
        int j = k*512 + tid;
        sxy[j] = make_float2(ob[3*j+0], ob[3*j+1]);
        sz[j]  = ob[3*j+2];
    }
    __syncthreads();

    for (int qi = 0; qi < QPW; ++qi) {
        const int n  = qb + w*QPW + qi;
        const float qx = ab[3*n+0], qy = ab[3*n+1], qz = ab[3*n+2];
        float dm = INF; int jm = 0;
        for (int t = 0; t < N_/64; ++t) {
            int j = t*64 + lane;
            float2 p = sxy[j]; float pz = sz[j];
            float dx = qx - p.x, dy = qy - p.y, dz = qz - pz;
            float d  = dx*dx + dy*dy + dz*dz;
            bool better = d < dm;               // keeps lowest index in-lane
            dm = better ? d : dm;
            jm = better ? j : jm;
        }
        for (int s = 1; s < 64; s <<= 1) {      // lexicographic (d, idx) min
            float od = __shfl_xor(dm, s);
            int   oj = __shfl_xor(jm, s);
            if (od < dm || (od == dm && oj < jm)) { dm = od; jm = oj; }
        }
        if (lane == 0) nnidx[b*N_ + n] = jm;
    }
}

// ---------------- kappa for both sets, accumulate (sum, sumsq) ---------------
__global__ __launch_bounds__(512, 6) void curv_kappa_kernel(
    const float* __restrict__ ori, const float* __restrict__ adv,
    const float* __restrict__ nrm, const int* __restrict__ nnidx,
    double* __restrict__ acc)
{
    __shared__ float2 sxy[N_];
    __shared__ float  sz[N_];
    __shared__ double rs[WAVES], rss[WAVES];
    const int tid  = threadIdx.x;
    const int lane = tid & 63;
    const int w    = tid >> 6;
    const int blk  = blockIdx.x;
    const int job  = blk >> 10;                 // 1024 blocks per job
    const int b    = (blk >> 8) & 3;
    const int qb   = (blk & 255) * QPB;

    const float* pb = (job ? adv : ori) + (size_t)b * (N_*3);
    const float* nb = nrm + (size_t)b * (N_*3);
    for (int k = 0; k < N_/512; ++k) {          // stage pts -> LDS
        int j = k*512 + tid;
        sxy[j] = make_float2(pb[3*j+0], pb[3*j+1]);
        sz[j]  = pb[3*j+2];
    }
    __syncthreads();

    double ws_s = 0.0, ws_ss = 0.0;
    for (int qi = 0; qi < QPW; ++qi) {
        const int n = qb + w*QPW + qi;
        const float2 qxy = sxy[n];
        const float  qz  = sz[n];
        int nn = n;
        if (job) nn = nnidx[b*N_ + n];
        const float nrx = nb[3*nn+0], nry = nb[3*nn+1], nrz = nb[3*nn+2];

        // ---- tile 0: bitonic sort 64 (d) ascending; ties don't affect
        //      top-16 MEMBERSHIP (kappa is an unordered mean) ----
        float d; int idx = lane;
        {
            float2 p = sxy[lane]; float pz = sz[lane];
            float dx = qxy.x - p.x, dy = qxy.y - p.y, dz = qz - pz;
            d = dx*dx + dy*dy + dz*dz;
            if (lane == n) d = INF;             // exclude self
        }
        #pragma unroll
        for (int k = 2; k <= 64; k <<= 1) {
            #pragma unroll
            for (int j = k >> 1; j > 0; j >>= 1) {
                float od = __shfl_xor(d, j);
                int   oi = __shfl_xor(idx, j);
                bool dirUp = ((lane & k) == 0);
                bool lower = ((lane & j) == 0);
                bool oless = (od < d);
                bool take  = (dirUp == lower) ? oless : !oless;
                if (take) { d = od; idx = oi; }
            }
        }
        float sd = d; int si = idx;             // lanes 0..15: sorted top-16
        float tau = readlane_f(sd, 15);
        const int selfT = n >> 6, selfL = n & 63;

        // ---- tiles 1..63: ballot + distributed insert (tau deferred) ----
        for (int t = 1; t < N_/64; ++t) {
            int j = t*64 + lane;
            float2 p = sxy[j]; float pz = sz[j];
            float dx = qxy.x - p.x, dy = qxy.y - p.y, dz = qz - pz;
            float dd = dx*dx + dy*dy + dz*dz;
            if (t == selfT && lane == selfL) dd = INF;
            unsigned long long mask = __ballot(dd < tau);
            if (mask) {
                do {
                    int src = __builtin_ctzll(mask);
                    mask &= mask - 1;
                    float v = readlane_f(dd, src);       // SGPR broadcast
                    int  vi = t*64 + src;
                    bool gt = (sd > v);
                    unsigned long long mg = __ballot(gt);
                    float usd = dpp_shr1_f(sd);
                    int   usi = dpp_shr1_i(si);
                    bool  pg  = ((mg << 1) >> lane) & 1ull;
                    sd = gt ? (pg ? usd : v ) : sd;      // insert is a no-op
                    si = gt ? (pg ? usi : vi) : si;      // if v >= sd[15]
                } while (mask);
                tau = readlane_f(sd, 15);
            }
        }

        // ---- kappa = mean_k |dot(normalize(nn - q), normal)| ----
        float tl = 0.0f;
        if (lane < K_) {
            float2 p = sxy[si]; float pz = sz[si];
            float vx = p.x - qxy.x, vy = p.y - qxy.y, vz = pz - qz;
            float L  = sqrtf(vx*vx + vy*vy + vz*vz) + 1e-12f;
            tl = fabsf(vx*nrx + vy*nry + vz*nrz) / L;
        }
        tl += __shfl_xor(tl, 1);
        tl += __shfl_xor(tl, 2);
        tl += __shfl_xor(tl, 4);
        tl += __shfl_xor(tl, 8);
        if (lane == 0) {
            double kap = (double)tl * (1.0/16.0);
            ws_s  += kap;
            ws_ss += kap * kap;
        }
    }

    if (lane == 0) { rs[w] = ws_s; rss[w] = ws_ss; }
    __syncthreads();
    if (tid == 0) {
        double s = 0.0, ss = 0.0;
        #pragma unroll
        for (int i = 0; i < WAVES; ++i) { s += rs[i]; ss += rss[i]; }
        int row = job*4 + b;
        atomicAdd(&acc[row*2+0], s);
        atomicAdd(&acc[row*2+1], ss);
    }
}

__global__ void curv_finalize_kernel(const double* __restrict__ acc,
                                     float* __restrict__ out)
{
    if (threadIdx.x == 0 && blockIdx.x == 0) {
        double st[8];
        #pragma unroll
        for (int r = 0; r < 8; ++r) {
            double s   = acc[2*r+0];
            double ss  = acc[2*r+1];
            double var = (ss - s*s / (double)N_) / (double)(N_ - 1);
            st[r] = var > 0.0 ? sqrt(var) : 0.0;
        }
        double o = 0.0;
        #pragma unroll
        for (int bb = 0; bb < 4; ++bb) o += fabs(st[4+bb] - st[bb]);
        out[0] = (float)(o * 0.25);
    }
}

extern "C" void kernel_launch(void* const* d_in, const int* in_sizes, int n_in,
                              void* d_out, int out_size, void* d_ws, size_t ws_size,
                              hipStream_t stream)
{
    const float* ori = (const float*)d_in[0];
    const float* adv = (const float*)d_in[1];
    const float* nrm = (const float*)d_in[2];
    double* acc   = (double*)d_ws;
    int*    nnidx = (int*)((char*)d_ws + 128);
    float*  out   = (float*)d_out;

    hipMemsetAsync(acc, 0, 16 * sizeof(double), stream);
    curv_argmin_kernel<<<dim3(B_ * BPB), 512, 0, stream>>>(ori, adv, nnidx);
    curv_kappa_kernel<<<dim3(2 * B_ * BPB), 512, 0, stream>>>(ori, adv, nrm, nnidx, acc);
    curv_finalize_kernel<<<1, 64, 0, stream>>>(acc, out);
}

// Round 4
// 117.294 us; speedup vs baseline: 5.8584x; 1.2481x over previous
//
#include <hip/hip_runtime.h>
#include <math.h>

#define B_ 4
#define N_ 4096
#define K_ 16
#define WAVES 8
#define QPB (WAVES*2)            // 2 queries per wave, fused in one tile loop
#define BPB (N_/QPB)             // 256 blocks per (job,b)
#define INF __builtin_huge_valf()

// shift value from lane-1 within each 16-lane row (lane%16==0 keeps own).
// Only lanes 0..15 (the distributed top-16 list) need the shift.
__device__ __forceinline__ float dpp_shr1_f(float x) {
    return __int_as_float(__builtin_amdgcn_update_dpp(
        __float_as_int(x), __float_as_int(x), 0x111, 0xF, 0xF, false));
}
__device__ __forceinline__ int dpp_shr1_i(int x) {
    return __builtin_amdgcn_update_dpp(x, x, 0x111, 0xF, 0xF, false);
}
__device__ __forceinline__ float readlane_f(float x, int l) {
    return __int_as_float(__builtin_amdgcn_readlane(__float_as_int(x), l));
}

// per-lane bit of a wave-uniform 64-bit mask, as a bool
#if __has_builtin(__builtin_amdgcn_inverse_ballot_w64)
#define LANEBIT(m, lane) __builtin_amdgcn_inverse_ballot_w64(m)
#else
#define LANEBIT(m, lane) ((((m) >> (lane)) & 1ull) != 0)
#endif

// ---------------- argmin(adv -> ori) : nn index per adv point ----------------
__global__ __launch_bounds__(512, 6) void curv_argmin_kernel(
    const float* __restrict__ ori, const float* __restrict__ adv,
    int* __restrict__ nnidx)
{
    __shared__ float2 sxy[N_];
    __shared__ float  sz[N_];
    const int tid = threadIdx.x, lane = tid & 63, w = tid >> 6;
    const int b  = blockIdx.x >> 8;
    const int qb = (blockIdx.x & 255) * QPB;
    const float* ob = ori + (size_t)b * (N_*3);
    const float* ab = adv + (size_t)b * (N_*3);
    for (int k = 0; k < N_/512; ++k) {
        int j = k*512 + tid;
        sxy[j] = make_float2(ob[3*j+0], ob[3*j+1]);
        sz[j]  = ob[3*j+2];
    }
    __syncthreads();

    const int n0 = qb + w*2, n1 = n0 + 1;
    const float m2x0 = -2.f*ab[3*n0+0], m2y0 = -2.f*ab[3*n0+1], m2z0 = -2.f*ab[3*n0+2];
    const float m2x1 = -2.f*ab[3*n1+0], m2y1 = -2.f*ab[3*n1+1], m2z1 = -2.f*ab[3*n1+2];

    // rank by r = |p|^2 - 2 q.p  (== d - |q|^2, the reference's own form)
    float dm0 = INF, dm1 = INF; int jm0 = 0, jm1 = 0;
    for (int t = 0; t < N_/64; ++t) {
        int j = t*64 + lane;
        float2 p = sxy[j]; float pz = sz[j];
        float pp = fmaf(pz,pz, fmaf(p.y,p.y, p.x*p.x));
        float r0 = fmaf(pz,m2z0, fmaf(p.y,m2y0, fmaf(p.x,m2x0, pp)));
        float r1 = fmaf(pz,m2z1, fmaf(p.y,m2y1, fmaf(p.x,m2x1, pp)));
        if (r0 < dm0) { dm0 = r0; jm0 = j; }    // strict: keeps earliest j
        if (r1 < dm1) { dm1 = r1; jm1 = j; }
    }
    for (int s = 1; s < 64; s <<= 1) {          // lexicographic (r, idx) min
        float o0 = __shfl_xor(dm0, s); int a0 = __shfl_xor(jm0, s);
        float o1 = __shfl_xor(dm1, s); int a1 = __shfl_xor(jm1, s);
        if (o0 < dm0 || (o0 == dm0 && a0 < jm0)) { dm0 = o0; jm0 = a0; }
        if (o1 < dm1 || (o1 == dm1 && a1 < jm1)) { dm1 = o1; jm1 = a1; }
    }
    if (lane == 0) { nnidx[b*N_+n0] = jm0; nnidx[b*N_+n1] = jm1; }
}

// ---------------- kappa for both sets, accumulate (sum, sumsq) ---------------
__global__ __launch_bounds__(512, 6) void curv_kappa_kernel(
    const float* __restrict__ ori, const float* __restrict__ adv,
    const float* __restrict__ nrm, const int* __restrict__ nnidx,
    double* __restrict__ acc)
{
    __shared__ float2 sxy[N_];
    __shared__ float  sz[N_];
    __shared__ double rs[WAVES], rss[WAVES];
    const int tid = threadIdx.x, lane = tid & 63, w = tid >> 6;
    const int blk = blockIdx.x;
    const int job = blk >> 10;                  // 1024 blocks per job
    const int b   = (blk >> 8) & 3;
    const int qb  = (blk & 255) * QPB;

    const float* pb = (job ? adv : ori) + (size_t)b*(N_*3);
    const float* nb = nrm + (size_t)b*(N_*3);
    for (int k = 0; k < N_/512; ++k) {
        int j = k*512 + tid;
        sxy[j] = make_float2(pb[3*j+0], pb[3*j+1]);
        sz[j]  = pb[3*j+2];
    }
    __syncthreads();

    const int n0 = qb + w*2, n1 = n0 + 1;       // n0 even -> same tile as n1
    const float2 q0 = sxy[n0]; const float q0z = sz[n0];
    const float2 q1 = sxy[n1]; const float q1z = sz[n1];
    const float m2x0 = -2.f*q0.x, m2y0 = -2.f*q0.y, m2z0 = -2.f*q0z;
    const float m2x1 = -2.f*q1.x, m2y1 = -2.f*q1.y, m2z1 = -2.f*q1z;

    int nn0 = n0, nn1 = n1;
    if (job) { nn0 = nnidx[b*N_+n0]; nn1 = nnidx[b*N_+n1]; }
    const float nx0 = nb[3*nn0+0], ny0 = nb[3*nn0+1], nz0 = nb[3*nn0+2];
    const float nx1 = nb[3*nn1+0], ny1 = nb[3*nn1+1], nz1 = nb[3*nn1+2];

    const int selfT = n0 >> 6;

    // ---- tile 0: expanded-form r + two interleaved bitonic sorts ----
    float r0, r1; int i0 = lane, i1 = lane;
    {
        float2 p = sxy[lane]; float pz = sz[lane];
        float pp = fmaf(pz,pz, fmaf(p.y,p.y, p.x*p.x));
        r0 = fmaf(pz,m2z0, fmaf(p.y,m2y0, fmaf(p.x,m2x0, pp)));
        r1 = fmaf(pz,m2z1, fmaf(p.y,m2y1, fmaf(p.x,m2x1, pp)));
        if (selfT == 0) {                       // exclude self
            if (lane == n0) r0 = INF;
            if (lane == n1) r1 = INF;
        }
    }
    #pragma unroll
    for (int k = 2; k <= 64; k <<= 1) {
        #pragma unroll
        for (int j = k >> 1; j > 0; j >>= 1) {
            bool sel = ((lane & k) == 0) == ((lane & j) == 0);
            float o0 = __shfl_xor(r0, j); int a0 = __shfl_xor(i0, j);
            float o1 = __shfl_xor(r1, j); int a1 = __shfl_xor(i1, j);
            if ((o0 < r0) == sel) { r0 = o0; i0 = a0; }
            if ((o1 < r1) == sel) { r1 = o1; i1 = a1; }
        }
    }
    float sd0 = r0, sd1 = r1; int si0 = i0, si1 = i1;   // lanes 0..15 sorted
    float tau0 = readlane_f(sd0, 15), tau1 = readlane_f(sd1, 15);
    const int selfL0 = n0 & 63, selfL1 = n1 & 63;

    // ---- tiles 1..63: one LDS read serves both queries ----
    for (int t = 1; t < N_/64; ++t) {
        int j = t*64 + lane;
        float2 p = sxy[j]; float pz = sz[j];
        float pp = fmaf(pz,pz, fmaf(p.y,p.y, p.x*p.x));
        float d0 = fmaf(pz,m2z0, fmaf(p.y,m2y0, fmaf(p.x,m2x0, pp)));
        float d1 = fmaf(pz,m2z1, fmaf(p.y,m2y1, fmaf(p.x,m2x1, pp)));
        if (t == selfT) {                       // scalar-guarded, fires once
            if (lane == selfL0) d0 = INF;
            if (lane == selfL1) d1 = INF;
        }
        unsigned long long m0 = __ballot(d0 < tau0);
        if (m0) {
            do {
                int src = __builtin_ctzll(m0); m0 &= m0 - 1;
                float v = readlane_f(d0, src);
                int  vi = t*64 + src;
                bool gt = (sd0 > v);
                unsigned long long mg = __ballot(gt);
                float usd = dpp_shr1_f(sd0); int usi = dpp_shr1_i(si0);
                bool pg = LANEBIT(mg << 1, lane);
                sd0 = gt ? (pg ? usd : v ) : sd0;
                si0 = gt ? (pg ? usi : vi) : si0;
            } while (m0);
            tau0 = readlane_f(sd0, 15);
        }
        unsigned long long m1 = __ballot(d1 < tau1);
        if (m1) {
            do {
                int src = __builtin_ctzll(m1); m1 &= m1 - 1;
                float v = readlane_f(d1, src);
                int  vi = t*64 + src;
                bool gt = (sd1 > v);
                unsigned long long mg = __ballot(gt);
                float usd = dpp_shr1_f(sd1); int usi = dpp_shr1_i(si1);
                bool pg = LANEBIT(mg << 1, lane);
                sd1 = gt ? (pg ? usd : v ) : sd1;
                si1 = gt ? (pg ? usi : vi) : si1;
            } while (m1);
            tau1 = readlane_f(sd1, 15);
        }
    }

    // ---- kappa = mean_k |dot(normalize(nn - q), normal)| ----
    float tl0 = 0.0f, tl1 = 0.0f;
    if (lane < K_) {
        {
            float2 p = sxy[si0]; float pz = sz[si0];
            float vx = p.x - q0.x, vy = p.y - q0.y, vz = pz - q0z;
            float L  = sqrtf(vx*vx + vy*vy + vz*vz) + 1e-12f;
            tl0 = fabsf(vx*nx0 + vy*ny0 + vz*nz0) / L;
        }
        {
            float2 p = sxy[si1]; float pz = sz[si1];
            float vx = p.x - q1.x, vy = p.y - q1.y, vz = pz - q1z;
            float L  = sqrtf(vx*vx + vy*vy + vz*vz) + 1e-12f;
            tl1 = fabsf(vx*nx1 + vy*ny1 + vz*nz1) / L;
        }
    }
    tl0 += __shfl_xor(tl0, 1); tl0 += __shfl_xor(tl0, 2);
    tl0 += __shfl_xor(tl0, 4); tl0 += __shfl_xor(tl0, 8);
    tl1 += __shfl_xor(tl1, 1); tl1 += __shfl_xor(tl1, 2);
    tl1 += __shfl_xor(tl1, 4); tl1 += __shfl_xor(tl1, 8);

    if (lane == 0) {
        double k0 = (double)tl0 * (1.0/16.0);
        double k1 = (double)tl1 * (1.0/16.0);
        rs[w]  = k0 + k1;
        rss[w] = k0*k0 + k1*k1;
    }
    __syncthreads();
    if (tid == 0) {
        double s = 0.0, ss = 0.0;
        #pragma unroll
        for (int i = 0; i < WAVES; ++i) { s += rs[i]; ss += rss[i]; }
        int row = job*4 + b;
        atomicAdd(&acc[row*2+0], s);
        atomicAdd(&acc[row*2+1], ss);
    }
}

__global__ void curv_finalize_kernel(const double* __restrict__ acc,
                                     float* __restrict__ out)
{
    if (threadIdx.x == 0 && blockIdx.x == 0) {
        double st[8];
        #pragma unroll
        for (int r = 0; r < 8; ++r) {
            double s   = acc[2*r+0];
            double ss  = acc[2*r+1];
            double var = (ss - s*s / (double)N_) / (double)(N_ - 1);
            st[r] = var > 0.0 ? sqrt(var) : 0.0;
        }
        double o = 0.0;
        #pragma unroll
        for (int bb = 0; bb < 4; ++bb) o += fabs(st[4+bb] - st[bb]);
        out[0] = (float)(o * 0.25);
    }
}

extern "C" void kernel_launch(void* const* d_in, const int* in_sizes, int n_in,
                              void* d_out, int out_size, void* d_ws, size_t ws_size,
                              hipStream_t stream)
{
    const float* ori = (const float*)d_in[0];
    const float* adv = (const float*)d_in[1];
    const float* nrm = (const float*)d_in[2];
    double* acc   = (double*)d_ws;
    int*    nnidx = (int*)((char*)d_ws + 128);
    float*  out   = (float*)d_out;

    hipMemsetAsync(acc, 0, 16 * sizeof(double), stream);
    curv_argmin_kernel<<<dim3(B_ * BPB), 512, 0, stream>>>(ori, adv, nnidx);
    curv_kappa_kernel<<<dim3(2 * B_ * BPB), 512, 0, stream>>>(ori, adv, nrm, nnidx, acc);
    curv_finalize_kernel<<<1, 64, 0, stream>>>(acc, out);
}